// Round 12
// baseline (424.757 us; speedup 1.0000x reference)
//
#include <hip/hip_runtime.h>
#include <hip/hip_fp16.h>

// SSIM, B=16, C=1, H=W=1024, 11x11 separable Gaussian.
// v11: v4 per-step code EXACTLY (proven fastest: 230us, absmax 0.0) with
// BAND halved 64->32: 12288 waves (2x TLP). Mechanism: v4 is latency-bound
// with VALU(145us)+DS(100us) barely overlapping at ~10 resident waves/CU;
// 48 offered waves/CU lets the pipes overlap across waves.
// Cost: +25% wave-steps (halo 20/52 vs 20/84) -- paid from idle cycles.
// Five structural attempts (readfirstlane/K=2 x2/fp16-pack/SW-pipeline) all
// lost to v4 by starving TLP or lengthening the chain; this raises TLP with
// zero per-step change. Also drops v4's 4 dead iterations (t<52 guard).
// Merged finalize (done-counter, validated v6/v7/v9/v10). launch_bounds(256,2)
// as v4 (VGPR 72, no spill).

#define IMG_H 1024
#define IMG_W 1024
#define USEC   44                      // useful cols per wave
#define NSTRIP 24                      // 24*44 = 1056 >= 1024
#define BAND   32                      // output rows per wave (v4: 64)
#define NBAND  32
#define NBATCH 16
#define NWAVES (NSTRIP * NBAND * NBATCH)   // 12288
#define NBLK   (NWAVES / 4)                // 3072 blocks of 4 waves
#define NSTEP  (BAND + 20)                 // 52 streamed rows per wave

__device__ __forceinline__ unsigned fkey(float f) {
  unsigned b = __float_as_uint(f);
  return (b & 0x80000000u) ? ~b : (b | 0x80000000u);
}
__device__ __forceinline__ float funkey(unsigned k) {
  return (k & 0x80000000u) ? __uint_as_float(k & 0x7FFFFFFFu)
                           : __uint_as_float(~k);
}
__device__ __forceinline__ unsigned xlane_u(unsigned v, int addr) {
  // full-wave (64-lane) register crossbar; addr in bytes, lane = addr[7:2]
  return (unsigned)__builtin_amdgcn_ds_bpermute(addr, (int)v);
}

__global__ void ssim_init(unsigned* __restrict__ ws) {
  ws[0] = 0u;           // sum S0*B0
  ws[1] = 0u;           // sum S0*B'   (C1 coefficient)
  ws[2] = 0u;           // sum B0*S'   (C2 coefficient)
  ws[3] = 0xFFFFFFFFu;  // min key
  ws[4] = 0u;           // max key
  ws[5] = 0u;           // done-counter
}

__global__ __launch_bounds__(256, 2)
void ssim_main(const float* __restrict__ img1, const float* __restrict__ img2,
               const float* __restrict__ kern, unsigned* __restrict__ ws,
               float* __restrict__ out) {
  __shared__ float redbuf[4][8];

  const int tid = threadIdx.x;
  const int lane = tid & 63;
  const int wv = tid >> 6;
  const int wid = blockIdx.x * 4 + wv;

  const int strip = wid % NSTRIP;
  const int rem = wid / NSTRIP;
  const int band = rem % NBAND;
  const int batch = rem / NBAND;

  const size_t boff = (size_t)batch * (IMG_H * IMG_W);
  const float* i1 = img1 + boff;
  const float* i2 = img2 + boff;

  // separable weights: g[j] = k2d[5][j] / sqrt(k2d[5][5]) (VGPRs; v7 showed
  // SGPR-pinning starves ILP)
  float g[11];
  #pragma unroll
  for (int j = 0; j < 11; ++j) g[j] = kern[55 + j] * rsqrtf(kern[60]);

  const int col = strip * USEC + lane - 10;    // absolute column of this lane
  const bool cok = (col >= 0) && (col < IMG_W);
  const int cidx = min(max(col, 0), IMG_W - 1);
  const bool oma = (lane >= 10) && (lane < 54) && (col < IMG_W); // output lane
  const int r0 = band * BAND;
  const int a4 = lane * 4;                     // bpermute self byte-address

  // rolling windows (statically indexed -> registers)
  float w1[11] = {}, w2[11] = {};
  float m1w[11] = {}, m2w[11] = {};
  float p11[11] = {}, p22[11] = {}, p12[11] = {};

  float acc0 = 0.f, aC1 = 0.f, aC2 = 0.f;
  float vmin = 1e30f, vmax = -1e30f;

  // prefetch row for t = 0 (img row r0-10)
  float nv1, nv2;
  {
    int rin = r0 - 10;
    if ((unsigned)rin < IMG_H) {
      nv1 = i1[(size_t)rin * IMG_W + cidx];
      nv2 = i2[(size_t)rin * IMG_W + cidx];
    } else { nv1 = 0.f; nv2 = 0.f; }
  }

  #pragma unroll 1
  for (int m = 0; m < 5; ++m) {
    #pragma unroll
    for (int c = 0; c < 11; ++c) {
      const int t = m * 11 + c;                // step; img row rt = r0-10+t
      if (t < NSTEP) {

        // commit prefetched row t (column-masked -> zero padding)
        float v1 = cok ? nv1 : 0.f;
        float v2 = cok ? nv2 : 0.f;
        w1[c] = v1; w2[c] = v2;
        vmin = fminf(vmin, fminf(v1, v2));     // pad zeros: negligible vs min
        vmax = fmaxf(vmax, fmaxf(v1, v2));

        // prefetch row t+1 (latency hidden under this step's compute)
        if (t < NSTEP - 1) {
          int rin = r0 - 9 + t;
          if ((unsigned)rin < IMG_H) {
            nv1 = i1[(size_t)rin * IMG_W + cidx];
            nv2 = i2[(size_t)rin * IMG_W + cidx];
          } else { nv1 = 0.f; nv2 = 0.f; }
        } else { nv1 = 0.f; nv2 = 0.f; }

        // vertical blur over img rows rt-10..rt -> Vimg at row rt-5
        float V1 = 0.f, V2 = 0.f;
        #pragma unroll
        for (int j = 0; j < 11; ++j) {
          V1 = fmaf(g[j], w1[(c + 1 + j) % 11], V1);
          V2 = fmaf(g[j], w2[(c + 1 + j) % 11], V2);
        }

        // horizontal blur via PACKED crossbar -> mu(rt-5).
        // (V1,V2) travel as one half2 word; center tap stays fp32.
        // Gaussian symmetric: g[5-o] == g[5+o] bitwise.
        unsigned pv;
        {
          __half2 pV = __floats2half2_rn(V1, V2);
          pv = *(unsigned*)&pV;
        }
        float mu1 = g[5] * V1, mu2 = g[5] * V2;
        #pragma unroll
        for (int o = 1; o <= 5; ++o) {
          unsigned ul = xlane_u(pv, a4 - 4 * o);
          unsigned ur = xlane_u(pv, a4 + 4 * o);
          __half2 hl = *(__half2*)&ul;
          __half2 hr = *(__half2*)&ur;
          float sg = g[5 + o];
          mu1 = fmaf(sg, __low2float(hl), mu1);
          mu1 = fmaf(sg, __low2float(hr), mu1);
          mu2 = fmaf(sg, __high2float(hl), mu2);
          mu2 = fmaf(sg, __high2float(hr), mu2);
        }
        m1w[c] = mu1; m2w[c] = mu2;

        // d at row rt-5 (0 outside the image, matching zero-padded 2nd conv)
        const bool drok = ((unsigned)(r0 - 15 + t) < IMG_H);
        float d1 = (drok && cok) ? (w1[(c + 6) % 11] - mu1) : 0.f;
        float d2 = (drok && cok) ? (w2[(c + 6) % 11] - mu2) : 0.f;

        // fused products + horizontal blur via PACKED crossbar of (d1,d2)
        unsigned pd;
        {
          __half2 pD = __floats2half2_rn(d1, d2);
          pd = *(unsigned*)&pD;
        }
        float h11 = (g[5] * d1) * d1;
        float h22 = (g[5] * d2) * d2;
        float h12 = (g[5] * d1) * d2;
        #pragma unroll
        for (int o = 1; o <= 5; ++o) {
          unsigned ul = xlane_u(pd, a4 - 4 * o);
          unsigned ur = xlane_u(pd, a4 + 4 * o);
          __half2 hl = *(__half2*)&ul;
          __half2 hr = *(__half2*)&ur;
          float l1 = __low2float(hl), l2 = __high2float(hl);
          float r1 = __low2float(hr), r2 = __high2float(hr);
          float u = g[5 + o];                  // == g[5 - o]
          h11 = fmaf(u, fmaf(l1, l1, r1 * r1), h11);
          h22 = fmaf(u, fmaf(l2, l2, r2 * r2), h22);
          h12 = fmaf(u, fmaf(l1, l2, r1 * r2), h12);
        }
        p11[c] = h11; p22[c] = h22; p12[c] = h12;

        // output row rt-10 (valid steps 20..NSTEP-1)
        if (t >= 20) {
          float s11 = 0.f, s22 = 0.f, s12 = 0.f;
          #pragma unroll
          for (int j = 0; j < 11; ++j) {
            float gj = g[j];
            s11 = fmaf(gj, p11[(c + 1 + j) % 11], s11);
            s22 = fmaf(gj, p22[(c + 1 + j) % 11], s22);
            s12 = fmaf(gj, p12[(c + 1 + j) % 11], s12);
          }
          float M1 = m1w[(c + 6) % 11], M2 = m2w[(c + 6) % 11];

          float s1 = s11 + 1.f;                // sigma1_sq
          float s2 = s22 + 1.f;                // sigma2_sq
          float sv = s12 + 1.f;                // sigma12
          float a = 2.f * sv;
          float b = s1 + s2;                   // >= 2 on valid lanes
          float rb = __builtin_amdgcn_rcpf(b);
          float S0 = a * rb;
          float Sp = (b - a) * rb * rb;        // dS/dC2
          float m12 = fmaf(M1, M2, 1.f);
          float nb = 2.f * m12;
          float N1 = nb * nb;
          float ms = fmaf(M1, M1, fmaf(M2, M2, 2.f));
          float Dv = ms * ms;                  // >= 4 on valid lanes
          float rD = __builtin_amdgcn_rcpf(Dv);
          float B0 = N1 * rD;
          float Bp = (Dv - N1) * rD * rD;      // dB/dC1
          float t0v = S0 * B0, t1v = S0 * Bp, t2v = B0 * Sp;
          acc0 += oma ? t0v : 0.f;             // select blocks NaN from halos
          aC1 += oma ? t1v : 0.f;
          aC2 += oma ? t2v : 0.f;
        }
      }
    }
  }

  // wave reduction (64 lanes), then block partials via tiny LDS
  #pragma unroll
  for (int off = 32; off > 0; off >>= 1) {
    acc0 += __shfl_down(acc0, off);
    aC1 += __shfl_down(aC1, off);
    aC2 += __shfl_down(aC2, off);
    vmin = fminf(vmin, __shfl_down(vmin, off));
    vmax = fmaxf(vmax, __shfl_down(vmax, off));
  }
  if (lane == 0) {
    redbuf[wv][0] = acc0; redbuf[wv][1] = aC1; redbuf[wv][2] = aC2;
    redbuf[wv][3] = vmin; redbuf[wv][4] = vmax;
  }
  __syncthreads();
  if (tid == 0) {
    float t0 = 0.f, t1 = 0.f, t2 = 0.f, mn = 1e30f, mx = -1e30f;
    #pragma unroll
    for (int w2 = 0; w2 < 4; ++w2) {
      t0 += redbuf[w2][0]; t1 += redbuf[w2][1]; t2 += redbuf[w2][2];
      mn = fminf(mn, redbuf[w2][3]); mx = fmaxf(mx, redbuf[w2][4]);
    }
    float* wsF = (float*)ws;
    atomicAdd(&wsF[0], t0);
    atomicAdd(&wsF[1], t1);
    atomicAdd(&wsF[2], t2);
    atomicMin(&ws[3], fkey(mn));
    atomicMax(&ws[4], fkey(mx));

    // finalize in the last block (validated done-counter)
    __threadfence();                           // device-scope: order ws ops
    unsigned done = atomicAdd(&ws[5], 1u);
    if (done == gridDim.x - 1) {
      float s0 = atomicAdd(&wsF[0], 0.f);      // device-scope atomic reads
      float sc1 = atomicAdd(&wsF[1], 0.f);
      float sc2 = atomicAdd(&wsF[2], 0.f);
      unsigned mnk = atomicMin(&ws[3], 0xFFFFFFFFu);
      unsigned mxk = atomicMax(&ws[4], 0u);
      float vr = funkey(mxk) - funkey(mnk) + 1e-5f;
      float c1 = 0.01f * vr; c1 *= c1;
      float c2 = 0.03f * vr; c2 *= c2;
      float mean = (s0 + c1 * sc1 + c2 * sc2) * (1.0f / 16777216.0f);
      out[0] = 1.f - mean;
    }
  }
}

extern "C" void kernel_launch(void* const* d_in, const int* in_sizes, int n_in,
                              void* d_out, int out_size, void* d_ws, size_t ws_size,
                              hipStream_t stream) {
  const float* img1 = (const float*)d_in[0];
  const float* img2 = (const float*)d_in[1];
  const float* kern = (const float*)d_in[2];
  unsigned* ws = (unsigned*)d_ws;
  float* out = (float*)d_out;
  (void)in_sizes; (void)n_in; (void)out_size; (void)ws_size;

  hipLaunchKernelGGL(ssim_init, dim3(1), dim3(1), 0, stream, ws);
  hipLaunchKernelGGL(ssim_main, dim3(NBLK), dim3(256), 0, stream,
                     img1, img2, kern, ws, out);
}

// Round 13
// 339.590 us; speedup vs baseline: 1.2508x; 1.2508x over previous
//
#include <hip/hip_runtime.h>
#include <hip/hip_fp16.h>

// SSIM, B=16, C=1, H=W=1024, 11x11 separable Gaussian.
// v12: v4 hot loop EXACTLY (champion: 230us, absmax 0.0) with the 20
// ds_bpermute/step replaced by DPP wave-shift chains (v5 retry):
//   WAVE_SHR1 (0x138): lane i <- i-1  (chained o times = tap -o)
//   WAVE_SHL1 (0x130): lane i <- i+1  (chained o times = tap +o)
//   bound_ctrl=1: edge lanes zero-fill -- touches only halo lanes that the
//   oma/consumer masks already block; output-lane math bit-identical to v4.
// Rationale: v5's "container failed twice" matches the infra signature of
// rounds 2-3 (same error on later-proven-good code); wave_shl1/shr1 are
// gfx9-family DPP controls and gfx950 is gfx9-lineage (LLVM rejects them
// only on gfx10+). An illegal control would be a COMPILE error, not a
// container failure. If this round again fails with container-failed-twice,
// that isolates DPP as the killer and it gets dropped permanently.
// Also: dead iterations t=84..87 trimmed (uniform guard, -4.5% work);
// merged finalize (validated v6/v7/v9/v10/v11); launch_bounds(256,2).
// Zero DS ops in the hot loop.

#define IMG_H 1024
#define IMG_W 1024
#define USEC   44                      // useful cols per wave
#define NSTRIP 24                      // 24*44 = 1056 >= 1024
#define BAND   64                      // output rows per wave
#define NBAND  16
#define NBATCH 16
#define NWAVES (NSTRIP * NBAND * NBATCH)   // 6144
#define NBLK   (NWAVES / 4)                // 1536 blocks of 4 waves

#define DPP_WF_SL1 0x130               // lane i <- lane i+1 (data shifts toward lane 0)
#define DPP_WF_SR1 0x138               // lane i <- lane i-1 (data shifts toward lane 63)

__device__ __forceinline__ unsigned fkey(float f) {
  unsigned b = __float_as_uint(f);
  return (b & 0x80000000u) ? ~b : (b | 0x80000000u);
}
__device__ __forceinline__ float funkey(unsigned k) {
  return (k & 0x80000000u) ? __uint_as_float(k & 0x7FFFFFFFu)
                           : __uint_as_float(~k);
}

__device__ __forceinline__ unsigned shl1(unsigned v) {   // lane i <- i+1, edge->0
  return (unsigned)__builtin_amdgcn_update_dpp(0, (int)v, DPP_WF_SL1, 0xF, 0xF, true);
}
__device__ __forceinline__ unsigned shr1(unsigned v) {   // lane i <- i-1, edge->0
  return (unsigned)__builtin_amdgcn_update_dpp(0, (int)v, DPP_WF_SR1, 0xF, 0xF, true);
}

__global__ void ssim_init(unsigned* __restrict__ ws) {
  ws[0] = 0u;           // sum S0*B0
  ws[1] = 0u;           // sum S0*B'   (C1 coefficient)
  ws[2] = 0u;           // sum B0*S'   (C2 coefficient)
  ws[3] = 0xFFFFFFFFu;  // min key
  ws[4] = 0u;           // max key
  ws[5] = 0u;           // done-counter
}

__global__ __launch_bounds__(256, 2)
void ssim_main(const float* __restrict__ img1, const float* __restrict__ img2,
               const float* __restrict__ kern, unsigned* __restrict__ ws,
               float* __restrict__ out) {
  __shared__ float redbuf[4][8];

  const int tid = threadIdx.x;
  const int lane = tid & 63;
  const int wv = tid >> 6;
  const int wid = blockIdx.x * 4 + wv;

  const int strip = wid % NSTRIP;
  const int rem = wid / NSTRIP;
  const int band = rem % NBAND;
  const int batch = rem / NBAND;

  const size_t boff = (size_t)batch * (IMG_H * IMG_W);
  const float* i1 = img1 + boff;
  const float* i2 = img2 + boff;

  // separable weights: g[j] = k2d[5][j] / sqrt(k2d[5][5]) (VGPRs; v7 showed
  // SGPR-pinning starves ILP)
  float g[11];
  #pragma unroll
  for (int j = 0; j < 11; ++j) g[j] = kern[55 + j] * rsqrtf(kern[60]);

  const int col = strip * USEC + lane - 10;    // absolute column of this lane
  const bool cok = (col >= 0) && (col < IMG_W);
  const int cidx = min(max(col, 0), IMG_W - 1);
  const bool oma = (lane >= 10) && (lane < 54) && (col < IMG_W); // output lane
  const int r0 = band * BAND;

  // rolling windows (statically indexed -> registers)
  float w1[11] = {}, w2[11] = {};
  float m1w[11] = {}, m2w[11] = {};
  float p11[11] = {}, p22[11] = {}, p12[11] = {};

  float acc0 = 0.f, aC1 = 0.f, aC2 = 0.f;
  float vmin = 1e30f, vmax = -1e30f;

  // prefetch row for t = 0 (img row r0-10)
  float nv1, nv2;
  {
    int rin = r0 - 10;
    if ((unsigned)rin < IMG_H) {
      nv1 = i1[(size_t)rin * IMG_W + cidx];
      nv2 = i2[(size_t)rin * IMG_W + cidx];
    } else { nv1 = 0.f; nv2 = 0.f; }
  }

  #pragma unroll 1
  for (int m = 0; m < 8; ++m) {
    #pragma unroll
    for (int c = 0; c < 11; ++c) {
      const int t = m * 11 + c;                // step; img row rt = r0-10+t
      if (t < 84) {                            // steps 84..87 fully dead

        // commit prefetched row t (column-masked -> zero padding)
        float v1 = cok ? nv1 : 0.f;
        float v2 = cok ? nv2 : 0.f;
        w1[c] = v1; w2[c] = v2;
        vmin = fminf(vmin, fminf(v1, v2));     // pad zeros: negligible vs min
        vmax = fmaxf(vmax, fmaxf(v1, v2));

        // prefetch row t+1 (latency hidden under this step's compute)
        if (t < 83) {
          int rin = r0 - 9 + t;
          if ((unsigned)rin < IMG_H) {
            nv1 = i1[(size_t)rin * IMG_W + cidx];
            nv2 = i2[(size_t)rin * IMG_W + cidx];
          } else { nv1 = 0.f; nv2 = 0.f; }
        } else { nv1 = 0.f; nv2 = 0.f; }

        // vertical blur over img rows rt-10..rt -> Vimg at row rt-5
        float V1 = 0.f, V2 = 0.f;
        #pragma unroll
        for (int j = 0; j < 11; ++j) {
          V1 = fmaf(g[j], w1[(c + 1 + j) % 11], V1);
          V2 = fmaf(g[j], w2[(c + 1 + j) % 11], V2);
        }

        // horizontal blur via packed DPP shift chains -> mu(rt-5).
        // (V1,V2) travel as one half2 word; center tap stays fp32.
        // Gaussian symmetric: g[5-o] == g[5+o] bitwise.
        unsigned pv;
        {
          __half2 pV = __floats2half2_rn(V1, V2);
          pv = *(unsigned*)&pV;
        }
        float mu1 = g[5] * V1, mu2 = g[5] * V2;
        {
          unsigned Lw = pv, Rw = pv;
          #pragma unroll
          for (int o = 1; o <= 5; ++o) {
            Lw = shr1(Lw);                     // lane i <- i-o (tap -o)
            Rw = shl1(Rw);                     // lane i <- i+o (tap +o)
            __half2 hl = *(__half2*)&Lw;
            __half2 hr = *(__half2*)&Rw;
            float sg = g[5 + o];
            mu1 = fmaf(sg, __low2float(hl), mu1);
            mu1 = fmaf(sg, __low2float(hr), mu1);
            mu2 = fmaf(sg, __high2float(hl), mu2);
            mu2 = fmaf(sg, __high2float(hr), mu2);
          }
        }
        m1w[c] = mu1; m2w[c] = mu2;

        // d at row rt-5 (0 outside the image, matching zero-padded 2nd conv)
        const bool drok = ((unsigned)(r0 - 15 + t) < IMG_H);
        float d1 = (drok && cok) ? (w1[(c + 6) % 11] - mu1) : 0.f;
        float d2 = (drok && cok) ? (w2[(c + 6) % 11] - mu2) : 0.f;

        // fused products + horizontal blur via packed DPP shifts of (d1,d2)
        unsigned pd;
        {
          __half2 pD = __floats2half2_rn(d1, d2);
          pd = *(unsigned*)&pD;
        }
        float h11 = (g[5] * d1) * d1;
        float h22 = (g[5] * d2) * d2;
        float h12 = (g[5] * d1) * d2;
        {
          unsigned Lw = pd, Rw = pd;
          #pragma unroll
          for (int o = 1; o <= 5; ++o) {
            Lw = shr1(Lw);
            Rw = shl1(Rw);
            __half2 hl = *(__half2*)&Lw;
            __half2 hr = *(__half2*)&Rw;
            float l1 = __low2float(hl), l2 = __high2float(hl);
            float r1 = __low2float(hr), r2 = __high2float(hr);
            float u = g[5 + o];                // == g[5 - o]
            h11 = fmaf(u, fmaf(l1, l1, r1 * r1), h11);
            h22 = fmaf(u, fmaf(l2, l2, r2 * r2), h22);
            h12 = fmaf(u, fmaf(l1, l2, r1 * r2), h12);
          }
        }
        p11[c] = h11; p22[c] = h22; p12[c] = h12;

        // output row rt-10 (valid steps 20..83)
        if (t >= 20) {
          float s11 = 0.f, s22 = 0.f, s12 = 0.f;
          #pragma unroll
          for (int j = 0; j < 11; ++j) {
            float gj = g[j];
            s11 = fmaf(gj, p11[(c + 1 + j) % 11], s11);
            s22 = fmaf(gj, p22[(c + 1 + j) % 11], s22);
            s12 = fmaf(gj, p12[(c + 1 + j) % 11], s12);
          }
          float M1 = m1w[(c + 6) % 11], M2 = m2w[(c + 6) % 11];

          float s1 = s11 + 1.f;                // sigma1_sq
          float s2 = s22 + 1.f;                // sigma2_sq
          float sv = s12 + 1.f;                // sigma12
          float a = 2.f * sv;
          float b = s1 + s2;                   // >= 2 on valid lanes
          float rb = __builtin_amdgcn_rcpf(b);
          float S0 = a * rb;
          float Sp = (b - a) * rb * rb;        // dS/dC2
          float m12 = fmaf(M1, M2, 1.f);
          float nb = 2.f * m12;
          float N1 = nb * nb;
          float ms = fmaf(M1, M1, fmaf(M2, M2, 2.f));
          float Dv = ms * ms;                  // >= 4 on valid lanes
          float rD = __builtin_amdgcn_rcpf(Dv);
          float B0 = N1 * rD;
          float Bp = (Dv - N1) * rD * rD;      // dB/dC1
          float t0v = S0 * B0, t1v = S0 * Bp, t2v = B0 * Sp;
          acc0 += oma ? t0v : 0.f;             // select blocks NaN from halos
          aC1 += oma ? t1v : 0.f;
          aC2 += oma ? t2v : 0.f;
        }
      }
    }
  }

  // wave reduction (64 lanes), then block partials via tiny LDS
  #pragma unroll
  for (int off = 32; off > 0; off >>= 1) {
    acc0 += __shfl_down(acc0, off);
    aC1 += __shfl_down(aC1, off);
    aC2 += __shfl_down(aC2, off);
    vmin = fminf(vmin, __shfl_down(vmin, off));
    vmax = fmaxf(vmax, __shfl_down(vmax, off));
  }
  if (lane == 0) {
    redbuf[wv][0] = acc0; redbuf[wv][1] = aC1; redbuf[wv][2] = aC2;
    redbuf[wv][3] = vmin; redbuf[wv][4] = vmax;
  }
  __syncthreads();
  if (tid == 0) {
    float t0 = 0.f, t1 = 0.f, t2 = 0.f, mn = 1e30f, mx = -1e30f;
    #pragma unroll
    for (int w2 = 0; w2 < 4; ++w2) {
      t0 += redbuf[w2][0]; t1 += redbuf[w2][1]; t2 += redbuf[w2][2];
      mn = fminf(mn, redbuf[w2][3]); mx = fmaxf(mx, redbuf[w2][4]);
    }
    float* wsF = (float*)ws;
    atomicAdd(&wsF[0], t0);
    atomicAdd(&wsF[1], t1);
    atomicAdd(&wsF[2], t2);
    atomicMin(&ws[3], fkey(mn));
    atomicMax(&ws[4], fkey(mx));

    // finalize in the last block (validated done-counter)
    __threadfence();                           // device-scope: order ws ops
    unsigned done = atomicAdd(&ws[5], 1u);
    if (done == gridDim.x - 1) {
      float s0 = atomicAdd(&wsF[0], 0.f);      // device-scope atomic reads
      float sc1 = atomicAdd(&wsF[1], 0.f);
      float sc2 = atomicAdd(&wsF[2], 0.f);
      unsigned mnk = atomicMin(&ws[3], 0xFFFFFFFFu);
      unsigned mxk = atomicMax(&ws[4], 0u);
      float vr = funkey(mxk) - funkey(mnk) + 1e-5f;
      float c1 = 0.01f * vr; c1 *= c1;
      float c2 = 0.03f * vr; c2 *= c2;
      float mean = (s0 + c1 * sc1 + c2 * sc2) * (1.0f / 16777216.0f);
      out[0] = 1.f - mean;
    }
  }
}

extern "C" void kernel_launch(void* const* d_in, const int* in_sizes, int n_in,
                              void* d_out, int out_size, void* d_ws, size_t ws_size,
                              hipStream_t stream) {
  const float* img1 = (const float*)d_in[0];
  const float* img2 = (const float*)d_in[1];
  const float* kern = (const float*)d_in[2];
  unsigned* ws = (unsigned*)d_ws;
  float* out = (float*)d_out;
  (void)in_sizes; (void)n_in; (void)out_size; (void)ws_size;

  hipLaunchKernelGGL(ssim_init, dim3(1), dim3(1), 0, stream, ws);
  hipLaunchKernelGGL(ssim_main, dim3(NBLK), dim3(256), 0, stream,
                     img1, img2, kern, ws, out);
}

// Round 14
// 311.659 us; speedup vs baseline: 1.3629x; 1.0896x over previous
//
#include <hip/hip_runtime.h>
#include <hip/hip_fp16.h>

// SSIM, B=16, C=1, H=W=1024, 11x11 separable Gaussian.
// v13: consolidation on the clean champion. EXACT v4 hot loop (230us,
// absmax 0.0: packed-half2 ds_bpermute exchanges, fp32 math, VGPR 72) +
// the one certain trim from v12 (skip dead iterations t=84..87, -4.5%).
// 3-LAUNCH STRUCTURE RESTORED: v7/v9/v12 isolated the merged finalize's
// per-block __threadfence (device-scope L2 writeback across 8 XCD L2s,
// 1536 blocks) as a common ~+20-30us kernel regression, while e2e launch
// gap stayed ~80-90us regardless of 2 vs 3 launches (merge saved nothing).
// Verdicts banked from 9 structural experiments: bpermute > DPP chains
// (serial dep) > serialized phases; K=1/6144 waves > K=2/2560; fp32 VALU
// with packed exchange words only; g[] in VGPRs; no cross-step pipeline.

#define IMG_H 1024
#define IMG_W 1024
#define USEC   44                      // useful cols per wave
#define NSTRIP 24                      // 24*44 = 1056 >= 1024
#define BAND   64                      // output rows per wave
#define NBAND  16
#define NBATCH 16
#define NWAVES (NSTRIP * NBAND * NBATCH)   // 6144
#define NBLK   (NWAVES / 4)                // 1536 blocks of 4 waves

__device__ __forceinline__ unsigned fkey(float f) {
  unsigned b = __float_as_uint(f);
  return (b & 0x80000000u) ? ~b : (b | 0x80000000u);
}
__device__ __forceinline__ float funkey(unsigned k) {
  return (k & 0x80000000u) ? __uint_as_float(k & 0x7FFFFFFFu)
                           : __uint_as_float(~k);
}

__device__ __forceinline__ unsigned xlane_u(unsigned v, int addr) {
  // full-wave (64-lane) register crossbar; addr in bytes, lane = addr[7:2]
  return (unsigned)__builtin_amdgcn_ds_bpermute(addr, (int)v);
}

__global__ void ssim_init(unsigned* __restrict__ ws) {
  ws[0] = 0u;           // sum S0*B0
  ws[1] = 0u;           // sum S0*B'   (C1 coefficient)
  ws[2] = 0u;           // sum B0*S'   (C2 coefficient)
  ws[3] = 0xFFFFFFFFu;  // min key
  ws[4] = 0u;           // max key
}

__global__ __launch_bounds__(256, 2)
void ssim_main(const float* __restrict__ img1, const float* __restrict__ img2,
               const float* __restrict__ kern, unsigned* __restrict__ ws) {
  __shared__ float redbuf[4][8];

  const int tid = threadIdx.x;
  const int lane = tid & 63;
  const int wv = tid >> 6;
  const int wid = blockIdx.x * 4 + wv;

  const int strip = wid % NSTRIP;
  const int rem = wid / NSTRIP;
  const int band = rem % NBAND;
  const int batch = rem / NBAND;

  const size_t boff = (size_t)batch * (IMG_H * IMG_W);
  const float* i1 = img1 + boff;
  const float* i2 = img2 + boff;

  // separable weights: g[j] = k2d[5][j] / sqrt(k2d[5][5]) (VGPRs; v7 showed
  // SGPR-pinning starves ILP)
  float g[11];
  #pragma unroll
  for (int j = 0; j < 11; ++j) g[j] = kern[55 + j] * rsqrtf(kern[60]);

  const int col = strip * USEC + lane - 10;    // absolute column of this lane
  const bool cok = (col >= 0) && (col < IMG_W);
  const int cidx = min(max(col, 0), IMG_W - 1);
  const bool oma = (lane >= 10) && (lane < 54) && (col < IMG_W); // output lane
  const int r0 = band * BAND;
  const int a4 = lane * 4;                     // bpermute self byte-address

  // rolling windows (statically indexed -> registers)
  float w1[11] = {}, w2[11] = {};
  float m1w[11] = {}, m2w[11] = {};
  float p11[11] = {}, p22[11] = {}, p12[11] = {};

  float acc0 = 0.f, aC1 = 0.f, aC2 = 0.f;
  float vmin = 1e30f, vmax = -1e30f;

  // prefetch row for t = 0 (img row r0-10)
  float nv1, nv2;
  {
    int rin = r0 - 10;
    if ((unsigned)rin < IMG_H) {
      nv1 = i1[(size_t)rin * IMG_W + cidx];
      nv2 = i2[(size_t)rin * IMG_W + cidx];
    } else { nv1 = 0.f; nv2 = 0.f; }
  }

  #pragma unroll 1
  for (int m = 0; m < 8; ++m) {
    #pragma unroll
    for (int c = 0; c < 11; ++c) {
      const int t = m * 11 + c;                // step; img row rt = r0-10+t
      if (t < 84) {                            // steps 84..87 fully dead

        // commit prefetched row t (column-masked -> zero padding)
        float v1 = cok ? nv1 : 0.f;
        float v2 = cok ? nv2 : 0.f;
        w1[c] = v1; w2[c] = v2;
        vmin = fminf(vmin, fminf(v1, v2));     // pad zeros: negligible vs min
        vmax = fmaxf(vmax, fmaxf(v1, v2));

        // prefetch row t+1 (latency hidden under this step's compute)
        if (t < 83) {
          int rin = r0 - 9 + t;
          if ((unsigned)rin < IMG_H) {
            nv1 = i1[(size_t)rin * IMG_W + cidx];
            nv2 = i2[(size_t)rin * IMG_W + cidx];
          } else { nv1 = 0.f; nv2 = 0.f; }
        } else { nv1 = 0.f; nv2 = 0.f; }

        // vertical blur over img rows rt-10..rt -> Vimg at row rt-5
        float V1 = 0.f, V2 = 0.f;
        #pragma unroll
        for (int j = 0; j < 11; ++j) {
          V1 = fmaf(g[j], w1[(c + 1 + j) % 11], V1);
          V2 = fmaf(g[j], w2[(c + 1 + j) % 11], V2);
        }

        // horizontal blur via PACKED crossbar -> mu(rt-5).
        // (V1,V2) travel as one half2 word; center tap stays fp32.
        // Gaussian symmetric: g[5-o] == g[5+o] bitwise.
        unsigned pv;
        {
          __half2 pV = __floats2half2_rn(V1, V2);
          pv = *(unsigned*)&pV;
        }
        float mu1 = g[5] * V1, mu2 = g[5] * V2;
        #pragma unroll
        for (int o = 1; o <= 5; ++o) {
          unsigned ul = xlane_u(pv, a4 - 4 * o);
          unsigned ur = xlane_u(pv, a4 + 4 * o);
          __half2 hl = *(__half2*)&ul;
          __half2 hr = *(__half2*)&ur;
          float sg = g[5 + o];
          mu1 = fmaf(sg, __low2float(hl), mu1);
          mu1 = fmaf(sg, __low2float(hr), mu1);
          mu2 = fmaf(sg, __high2float(hl), mu2);
          mu2 = fmaf(sg, __high2float(hr), mu2);
        }
        m1w[c] = mu1; m2w[c] = mu2;

        // d at row rt-5 (0 outside the image, matching zero-padded 2nd conv)
        const bool drok = ((unsigned)(r0 - 15 + t) < IMG_H);
        float d1 = (drok && cok) ? (w1[(c + 6) % 11] - mu1) : 0.f;
        float d2 = (drok && cok) ? (w2[(c + 6) % 11] - mu2) : 0.f;

        // fused products + horizontal blur via PACKED crossbar of (d1,d2)
        unsigned pd;
        {
          __half2 pD = __floats2half2_rn(d1, d2);
          pd = *(unsigned*)&pD;
        }
        float h11 = (g[5] * d1) * d1;
        float h22 = (g[5] * d2) * d2;
        float h12 = (g[5] * d1) * d2;
        #pragma unroll
        for (int o = 1; o <= 5; ++o) {
          unsigned ul = xlane_u(pd, a4 - 4 * o);
          unsigned ur = xlane_u(pd, a4 + 4 * o);
          __half2 hl = *(__half2*)&ul;
          __half2 hr = *(__half2*)&ur;
          float l1 = __low2float(hl), l2 = __high2float(hl);
          float r1 = __low2float(hr), r2 = __high2float(hr);
          float u = g[5 + o];                  // == g[5 - o]
          h11 = fmaf(u, fmaf(l1, l1, r1 * r1), h11);
          h22 = fmaf(u, fmaf(l2, l2, r2 * r2), h22);
          h12 = fmaf(u, fmaf(l1, l2, r1 * r2), h12);
        }
        p11[c] = h11; p22[c] = h22; p12[c] = h12;

        // output row rt-10 (valid steps 20..83)
        if (t >= 20) {
          float s11 = 0.f, s22 = 0.f, s12 = 0.f;
          #pragma unroll
          for (int j = 0; j < 11; ++j) {
            float gj = g[j];
            s11 = fmaf(gj, p11[(c + 1 + j) % 11], s11);
            s22 = fmaf(gj, p22[(c + 1 + j) % 11], s22);
            s12 = fmaf(gj, p12[(c + 1 + j) % 11], s12);
          }
          float M1 = m1w[(c + 6) % 11], M2 = m2w[(c + 6) % 11];

          float s1 = s11 + 1.f;                // sigma1_sq
          float s2 = s22 + 1.f;                // sigma2_sq
          float sv = s12 + 1.f;                // sigma12
          float a = 2.f * sv;
          float b = s1 + s2;                   // >= 2 on valid lanes
          float rb = __builtin_amdgcn_rcpf(b);
          float S0 = a * rb;
          float Sp = (b - a) * rb * rb;        // dS/dC2
          float m12 = fmaf(M1, M2, 1.f);
          float nb = 2.f * m12;
          float N1 = nb * nb;
          float ms = fmaf(M1, M1, fmaf(M2, M2, 2.f));
          float Dv = ms * ms;                  // >= 4 on valid lanes
          float rD = __builtin_amdgcn_rcpf(Dv);
          float B0 = N1 * rD;
          float Bp = (Dv - N1) * rD * rD;      // dB/dC1
          float t0v = S0 * B0, t1v = S0 * Bp, t2v = B0 * Sp;
          acc0 += oma ? t0v : 0.f;             // select blocks NaN from halos
          aC1 += oma ? t1v : 0.f;
          aC2 += oma ? t2v : 0.f;
        }
      }
    }
  }

  // wave reduction (64 lanes), then block partials via tiny LDS
  #pragma unroll
  for (int off = 32; off > 0; off >>= 1) {
    acc0 += __shfl_down(acc0, off);
    aC1 += __shfl_down(aC1, off);
    aC2 += __shfl_down(aC2, off);
    vmin = fminf(vmin, __shfl_down(vmin, off));
    vmax = fmaxf(vmax, __shfl_down(vmax, off));
  }
  if (lane == 0) {
    redbuf[wv][0] = acc0; redbuf[wv][1] = aC1; redbuf[wv][2] = aC2;
    redbuf[wv][3] = vmin; redbuf[wv][4] = vmax;
  }
  __syncthreads();
  if (tid == 0) {
    float t0 = 0.f, t1 = 0.f, t2 = 0.f, mn = 1e30f, mx = -1e30f;
    #pragma unroll
    for (int w2 = 0; w2 < 4; ++w2) {
      t0 += redbuf[w2][0]; t1 += redbuf[w2][1]; t2 += redbuf[w2][2];
      mn = fminf(mn, redbuf[w2][3]); mx = fmaxf(mx, redbuf[w2][4]);
    }
    float* wsF = (float*)ws;
    atomicAdd(&wsF[0], t0);
    atomicAdd(&wsF[1], t1);
    atomicAdd(&wsF[2], t2);
    atomicMin(&ws[3], fkey(mn));
    atomicMax(&ws[4], fkey(mx));
  }
}

__global__ void ssim_final(const unsigned* __restrict__ ws, float* __restrict__ out) {
  const float* wsF = (const float*)ws;
  float mn = funkey(ws[3]);
  float mx = funkey(ws[4]);
  float vr = mx - mn + 1e-5f;
  float c1 = 0.01f * vr; c1 *= c1;
  float c2 = 0.03f * vr; c2 *= c2;
  float mean = (wsF[0] + c1 * wsF[1] + c2 * wsF[2]) * (1.0f / 16777216.0f);
  out[0] = 1.f - mean;
}

extern "C" void kernel_launch(void* const* d_in, const int* in_sizes, int n_in,
                              void* d_out, int out_size, void* d_ws, size_t ws_size,
                              hipStream_t stream) {
  const float* img1 = (const float*)d_in[0];
  const float* img2 = (const float*)d_in[1];
  const float* kern = (const float*)d_in[2];
  unsigned* ws = (unsigned*)d_ws;
  float* out = (float*)d_out;
  (void)in_sizes; (void)n_in; (void)out_size; (void)ws_size;

  hipLaunchKernelGGL(ssim_init, dim3(1), dim3(1), 0, stream, ws);
  hipLaunchKernelGGL(ssim_main, dim3(NBLK), dim3(256), 0, stream,
                     img1, img2, kern, ws);
  hipLaunchKernelGGL(ssim_final, dim3(1), dim3(1), 0, stream, ws, out);
}